// Round 1
// baseline (482.926 us; speedup 1.0000x reference)
//
#include <hip/hip_runtime.h>
#include <stdint.h>

typedef short short8 __attribute__((ext_vector_type(8)));
typedef float f32x4 __attribute__((ext_vector_type(4)));

#define KLAM 0.003f
// B=2, H=2048, L=4096, Lk=128, N = B*L = 8192, M2 = 2H = 4096

__device__ __forceinline__ uint16_t f2bf(float f) {
  union { float f; uint32_t u; } v; v.f = f;
  uint32_t r = v.u + 0x7fffu + ((v.u >> 16) & 1u);  // RNE
  return (uint16_t)(r >> 16);
}
__device__ __forceinline__ uint32_t pack_lo(uint32_t a, uint32_t b) { return (a & 0xffffu) | (b << 16); }
__device__ __forceinline__ uint32_t pack_hi(uint32_t a, uint32_t b) { return (a >> 16) | (b & 0xffff0000u); }
__device__ __forceinline__ int swzB(int n) { return ((n & 7) ^ ((n >> 3) & 7)); }

// ---------------- K1: cast W_out (f32 [4096][2048]) -> bf16 ----------------
__global__ __launch_bounds__(256) void cast_w_kernel(const float* __restrict__ W,
                                                     uint16_t* __restrict__ Wb) {
  int i = (blockIdx.x * 256 + threadIdx.x) * 8;
  float4 f0 = *(const float4*)(W + i);
  float4 f1 = *(const float4*)(W + i + 4);
  uint4 q;
  q.x = (uint32_t)f2bf(f0.x) | ((uint32_t)f2bf(f0.y) << 16);
  q.y = (uint32_t)f2bf(f0.z) | ((uint32_t)f2bf(f0.w) << 16);
  q.z = (uint32_t)f2bf(f1.x) | ((uint32_t)f2bf(f1.y) << 16);
  q.w = (uint32_t)f2bf(f1.z) | ((uint32_t)f2bf(f1.w) << 16);
  *(uint4*)(Wb + i) = q;
}

// ------- K2: depthwise causal FIR (128 taps) + u*D + exact GeLU -> X bf16 [2048][8192] -------
__global__ __launch_bounds__(256) void conv_gelu_kernel(const float* __restrict__ u,
                                                        const float* __restrict__ kern,
                                                        const float* __restrict__ D,
                                                        uint16_t* __restrict__ X) {
  __shared__ float su[4096];
  __shared__ float sk[128];
  int tid = threadIdx.x;
  int bh = blockIdx.x;            // b*2048 + h
  int h = bh & 2047;
  int b = bh >> 11;

  const float4* u4 = (const float4*)(u + (size_t)bh * 4096);
  float4* s4 = (float4*)su;
#pragma unroll
  for (int i = 0; i < 4; ++i) s4[i * 256 + tid] = u4[i * 256 + tid];
  if (tid < 128) {
    float kv = kern[h * 128 + tid];
    float a = fabsf(kv) - KLAM;
    sk[tid] = (a > 0.f) ? (kv > 0.f ? a : -a) : 0.f;  // soft-threshold
  }
  __syncthreads();

  float Dh = D[h];
  int l0 = tid * 16;
  float acc[16], w[16];
#pragma unroll
  for (int i = 0; i < 16; ++i) { w[i] = su[l0 + i]; acc[i] = 0.f; }
  // sliding 16-register circular window: w[p] holds u[pos] with pos == p (mod 16)
#pragma unroll
  for (int j = 0; j < 128; ++j) {
    float kj = sk[j];
#pragma unroll
    for (int i = 0; i < 16; ++i) acc[i] = fmaf(kj, w[(i - j) & 15], acc[i]);
    int pos = l0 - j - 1;
    float nv = 0.f;
    if (pos >= 0) nv = su[pos];   // causal zero-pad
    w[(-j - 1) & 15] = nv;
  }

  uint16_t us[16];
#pragma unroll
  for (int i = 0; i < 16; ++i) {
    float y = acc[i] + Dh * su[l0 + i];
    float g = 0.5f * y * (1.f + erff(y * 0.70710678118654752f));  // exact GeLU
    us[i] = f2bf(g);
  }
  uint32_t p[8];
#pragma unroll
  for (int i = 0; i < 8; ++i) p[i] = (uint32_t)us[2 * i] | ((uint32_t)us[2 * i + 1] << 16);
  size_t xo = (size_t)h * 8192 + (size_t)b * 4096 + l0;
  uint4 q0; q0.x = p[0]; q0.y = p[1]; q0.z = p[2]; q0.w = p[3];
  uint4 q1; q1.x = p[4]; q1.y = p[5]; q1.z = p[6]; q1.w = p[7];
  *(uint4*)(X + xo) = q0;
  *(uint4*)(X + xo + 8) = q1;
}

// ------- K3: GEMM (Y = Wb * X) + bias + fused GLU -> out f32 [2][2048][4096] -------
// Block tile: 64 a-rows (o=m0..m0+63) + 64 g-rows (o+2048), 128 cols, BK=64, double-buffered.
// 256 threads = 4 waves; wave (wv>>1, wv&1) owns 32a+32g rows x 64 cols = 16 mfma frags.
__global__ __launch_bounds__(256, 2) void gemm_glu_kernel(const uint16_t* __restrict__ Wb,
                                                          const uint16_t* __restrict__ X,
                                                          const float* __restrict__ bout,
                                                          float* __restrict__ out) {
  __shared__ char lds[65536];   // As[2][128][64]b16 @0, Bs[2][128 n][64 k]b16 @32768 (both XOR-swizzled)

  int tid = threadIdx.x;
  int lane = tid & 63;
  int wv = tid >> 6;

  // bijective XCD swizzle (nwg=2048 divisible by 8)
  int bid = blockIdx.x;
  int wg = (bid & 7) * 256 + (bid >> 3);
  int bm = wg >> 6, bn = wg & 63;
  int m0 = bm * 64, n0 = bn * 128;

  // ---- A staging coords: 4 chunks of 16B/thread; chunk c = i*256+tid -> row r=c>>3, byte (c&7)*16
  int arb = tid >> 3;           // + i*32
  int ab = (tid & 7) * 16;
  const char* Aglob[4];
  uint32_t AwAddr[4];
#pragma unroll
  for (int i = 0; i < 4; ++i) {
    int r = i * 32 + arb;       // 0..127 ; rows 0-63 = a (W rows m0+r), 64-127 = g (W rows 2048+m0+r-64)
    int o = (r < 64) ? (m0 + r) : (2048 + m0 + (r - 64));
    Aglob[i] = (const char*)Wb + (size_t)o * 4096 + ab;     // row stride 2048*2B
    AwAddr[i] = (uint32_t)(r * 128 + (ab ^ ((r & 7) << 4)));
  }
  // ---- B staging coords: thread covers 8 k-rows x 4 n; loads 8x uint2, writes 4x b128 transposed
  int n4 = (tid & 31) * 4;
  int kg = (tid >> 5) * 8;
  const char* Bglob = (const char*)X + ((size_t)kg * 8192 + (size_t)(n0 + n4)) * 2;
  uint32_t BwAddr[4];
#pragma unroll
  for (int no = 0; no < 4; ++no) {
    int n = n4 + no;
    BwAddr[no] = (uint32_t)(n * 128 + (((tid >> 5) * 16) ^ (swzB(n) << 4)));
  }

  f32x4 zero = {0.f, 0.f, 0.f, 0.f};
  f32x4 acc_a[2][4], acc_g[2][4];
#pragma unroll
  for (int mi = 0; mi < 2; ++mi)
#pragma unroll
    for (int ni = 0; ni < 4; ++ni) { acc_a[mi][ni] = zero; acc_g[mi][ni] = zero; }

  uint4 aR[4];
  uint2 bR[8];
  auto LOAD = [&](int t) {
    size_t koff = (size_t)t * 128;              // BK*2 bytes along k
#pragma unroll
    for (int i = 0; i < 4; ++i) aR[i] = *(const uint4*)(Aglob[i] + koff);
    size_t bko = (size_t)t * 64 * 16384;        // BK rows * 8192*2 bytes
#pragma unroll
    for (int i = 0; i < 8; ++i) bR[i] = *(const uint2*)(Bglob + bko + (size_t)i * 16384);
  };
  auto WRITE = [&](int buf) {
    char* A = lds + buf * 16384;
#pragma unroll
    for (int i = 0; i < 4; ++i) *(uint4*)(A + AwAddr[i]) = aR[i];
    char* Bb = lds + 32768 + buf * 16384;
    {
      uint4 q; q.x = pack_lo(bR[0].x, bR[1].x); q.y = pack_lo(bR[2].x, bR[3].x);
      q.z = pack_lo(bR[4].x, bR[5].x); q.w = pack_lo(bR[6].x, bR[7].x);
      *(uint4*)(Bb + BwAddr[0]) = q;
    }
    {
      uint4 q; q.x = pack_hi(bR[0].x, bR[1].x); q.y = pack_hi(bR[2].x, bR[3].x);
      q.z = pack_hi(bR[4].x, bR[5].x); q.w = pack_hi(bR[6].x, bR[7].x);
      *(uint4*)(Bb + BwAddr[1]) = q;
    }
    {
      uint4 q; q.x = pack_lo(bR[0].y, bR[1].y); q.y = pack_lo(bR[2].y, bR[3].y);
      q.z = pack_lo(bR[4].y, bR[5].y); q.w = pack_lo(bR[6].y, bR[7].y);
      *(uint4*)(Bb + BwAddr[2]) = q;
    }
    {
      uint4 q; q.x = pack_hi(bR[0].y, bR[1].y); q.y = pack_hi(bR[2].y, bR[3].y);
      q.z = pack_hi(bR[4].y, bR[5].y); q.w = pack_hi(bR[6].y, bR[7].y);
      *(uint4*)(Bb + BwAddr[3]) = q;
    }
  };

  LOAD(0);
  WRITE(0);
  __syncthreads();

  for (int t = 0; t < 32; ++t) {
    int cur = t & 1;
    if (t < 31) LOAD(t + 1);

    const char* A = lds + cur * 16384;
    const char* Bb = lds + 32768 + cur * 16384;
#pragma unroll
    for (int kk = 0; kk < 2; ++kk) {
      int kbyte = kk * 64 + ((lane >> 4) << 4);   // 2*(kk*32 + (lane>>4)*8)
      short8 fa[2], fg[2], fb[4];
#pragma unroll
      for (int mi = 0; mi < 2; ++mi) {
        int ra = (wv >> 1) * 32 + mi * 16 + (lane & 15);
        fa[mi] = *(const short8*)(A + ra * 128 + (kbyte ^ ((ra & 7) << 4)));
        int rg = 64 + ra;
        fg[mi] = *(const short8*)(A + rg * 128 + (kbyte ^ ((rg & 7) << 4)));
      }
#pragma unroll
      for (int ni = 0; ni < 4; ++ni) {
        int n = (wv & 1) * 64 + ni * 16 + (lane & 15);
        fb[ni] = *(const short8*)(Bb + n * 128 + (kbyte ^ (swzB(n) << 4)));
      }
#pragma unroll
      for (int mi = 0; mi < 2; ++mi)
#pragma unroll
        for (int ni = 0; ni < 4; ++ni) {
          acc_a[mi][ni] = __builtin_amdgcn_mfma_f32_16x16x32_bf16(fa[mi], fb[ni], acc_a[mi][ni], 0, 0, 0);
          acc_g[mi][ni] = __builtin_amdgcn_mfma_f32_16x16x32_bf16(fg[mi], fb[ni], acc_g[mi][ni], 0, 0, 0);
        }
    }

    if (t < 31) WRITE(cur ^ 1);
    __syncthreads();
  }

  // ---- epilogue: bias + GLU (a * sigmoid(g)), write f32 out [b][h][l]
  int colb = n0 + (wv & 1) * 64;
#pragma unroll
  for (int mi = 0; mi < 2; ++mi) {
    int ob = m0 + (wv >> 1) * 32 + mi * 16 + ((lane >> 4) << 2);
#pragma unroll
    for (int q = 0; q < 4; ++q) {
      int o = ob + q;
      float ba = bout[o];
      float bg = bout[o + 2048];
#pragma unroll
      for (int ni = 0; ni < 4; ++ni) {
        float av = acc_a[mi][ni][q] + ba;
        float gv = acc_g[mi][ni][q] + bg;
        float res = av / (1.f + expf(-gv));
        int n = colb + ni * 16 + (lane & 15);
        out[(size_t)(n >> 12) * 8388608 + (size_t)o * 4096 + (n & 4095)] = res;
      }
    }
  }
}

extern "C" void kernel_launch(void* const* d_in, const int* in_sizes, int n_in,
                              void* d_out, int out_size, void* d_ws, size_t ws_size,
                              hipStream_t stream) {
  const float* u    = (const float*)d_in[0];   // [2][2048][4096]
  const float* kern = (const float*)d_in[1];   // [1][2048][128]
  const float* D    = (const float*)d_in[2];   // [1][2048]
  const float* W    = (const float*)d_in[3];   // [4096][2048]
  const float* bo   = (const float*)d_in[4];   // [4096]
  float* out = (float*)d_out;                  // [2][2048][4096] f32

  uint16_t* Wb = (uint16_t*)d_ws;                                   // 16 MB
  uint16_t* X  = (uint16_t*)((char*)d_ws + (size_t)4096 * 2048 * 2); // 32 MB, [2048][8192]

  hipLaunchKernelGGL(cast_w_kernel,    dim3(4096), dim3(256), 0, stream, W, Wb);
  hipLaunchKernelGGL(conv_gelu_kernel, dim3(4096), dim3(256), 0, stream, u, kern, D, X);
  hipLaunchKernelGGL(gemm_glu_kernel,  dim3(2048), dim3(256), 0, stream, Wb, X, bo, out);
}

// Round 2
// 287.404 us; speedup vs baseline: 1.6803x; 1.6803x over previous
//
#include <hip/hip_runtime.h>
#include <stdint.h>

typedef short short8 __attribute__((ext_vector_type(8)));
typedef float f32x4 __attribute__((ext_vector_type(4)));

#define KLAM 0.003f
// B=2, H=2048, L=4096, Lk=128, N = B*L = 8192, M2 = 2H = 4096

__device__ __forceinline__ uint16_t f2bf(float f) {
  union { float f; uint32_t u; } v; v.f = f;
  uint32_t r = v.u + 0x7fffu + ((v.u >> 16) & 1u);  // RNE
  return (uint16_t)(r >> 16);
}
__device__ __forceinline__ uint32_t pack_lo(uint32_t a, uint32_t b) { return (a & 0xffffu) | (b << 16); }
__device__ __forceinline__ uint32_t pack_hi(uint32_t a, uint32_t b) { return (a >> 16) | (b & 0xffff0000u); }
__device__ __forceinline__ int swzB(int n) { return ((n & 7) ^ ((n >> 3) & 7)); }

// ---------------- K1: cast W_out (f32 [4096][2048]) -> bf16 ----------------
__global__ __launch_bounds__(256) void cast_w_kernel(const float* __restrict__ W,
                                                     uint16_t* __restrict__ Wb) {
  int i = (blockIdx.x * 256 + threadIdx.x) * 8;
  float4 f0 = *(const float4*)(W + i);
  float4 f1 = *(const float4*)(W + i + 4);
  uint4 q;
  q.x = (uint32_t)f2bf(f0.x) | ((uint32_t)f2bf(f0.y) << 16);
  q.y = (uint32_t)f2bf(f0.z) | ((uint32_t)f2bf(f0.w) << 16);
  q.z = (uint32_t)f2bf(f1.x) | ((uint32_t)f2bf(f1.y) << 16);
  q.w = (uint32_t)f2bf(f1.z) | ((uint32_t)f2bf(f1.w) << 16);
  *(uint4*)(Wb + i) = q;
}

// ------- K2: depthwise causal FIR (128 taps) via MFMA Toeplitz + u*D + exact GeLU -------
// One block per (b,h). Outputs tiled 256-wide: t = T0 + 16m + n (m,n in [0,16)).
// D[m][n] = sum_{q=0..4} A_q x B_q, A_q[m][j] = u_bf16[T0+16m-16-32q+j] (j=0..31),
// B_q[j][n] = khat[n+16+32q-j] (zero-padded). Exactly covers taps d in [0,128).
__global__ __launch_bounds__(256) void conv_gelu_kernel(const float* __restrict__ u,
                                                        const float* __restrict__ kern,
                                                        const float* __restrict__ D,
                                                        uint16_t* __restrict__ X) {
  __shared__ __align__(16) float su[4096];        // f32 row (for skip term)
  __shared__ __align__(16) uint16_t ubf[4256];    // bf16 row, 160 zero-pad front
  __shared__ __align__(16) uint16_t kR[176];      // reversed padded bf16 kernel: kR[z]=khat[159-z]
  __shared__ __align__(16) uint16_t stg[4][256];  // per-wave output stage

  int tid = threadIdx.x;
  int bh = blockIdx.x;            // b*2048 + h
  int h = bh & 2047;
  int b = bh >> 11;
  int lane = tid & 63;
  int wv = tid >> 6;
  int ln15 = lane & 15;           // A-row m fine idx == B-col n
  int g = lane >> 4;              // K-group

  // ---- stage u row: f32 + bf16 copies
  const float4* u4 = (const float4*)(u + (size_t)bh * 4096);
#pragma unroll
  for (int i = 0; i < 4; ++i) {
    float4 v = u4[i * 256 + tid];
    ((float4*)su)[i * 256 + tid] = v;
    uint2 p;
    p.x = (uint32_t)f2bf(v.x) | ((uint32_t)f2bf(v.y) << 16);
    p.y = (uint32_t)f2bf(v.z) | ((uint32_t)f2bf(v.w) << 16);
    *(uint2*)(ubf + 160 + (i * 256 + tid) * 4) = p;
  }
  if (tid < 40) { uint2 z; z.x = 0; z.y = 0; *(uint2*)(ubf + tid * 4) = z; }
  // ---- reversed, soft-thresholded, zero-padded kernel (bf16)
  if (tid < 176) {
    int i = 159 - tid;
    uint16_t r = 0;
    if (i >= 0 && i < 128) {
      float kv = kern[h * 128 + i];
      float a = fabsf(kv) - KLAM;
      float s = (a > 0.f) ? (kv > 0.f ? a : -a) : 0.f;
      r = f2bf(s);
    }
    kR[tid] = r;
  }
  __syncthreads();

  float Dh = D[h];

  // ---- build 5 B fragments (reused for all tiles): elem e = khat[n+16+32q-8g-e] = kR[z0+e]
  short8 bfr[5];
#pragma unroll
  for (int q = 0; q < 5; ++q) {
    int z0 = 143 - 32 * q - ln15 + 8 * g;   // in [0, 167]
    union { short8 v; uint16_t s[8]; } t;
#pragma unroll
    for (int e = 0; e < 8; ++e) t.s[e] = kR[z0 + e];
    bfr[q] = t.v;
  }

  // ---- 4 tiles of 256 outputs per wave
#pragma unroll
  for (int it = 0; it < 4; ++it) {
    int T0 = (wv * 4 + it) * 256;
    f32x4 acc = {0.f, 0.f, 0.f, 0.f};
#pragma unroll
    for (int q = 0; q < 5; ++q) {
      // A_q: start elem = 160 + T0 + 16*m - 16 - 32q + 8g  (16B aligned, in [16, 4248])
      const short8 a = *(const short8*)(ubf + 160 + T0 + 16 * ln15 - 16 - 32 * q + 8 * g);
      acc = __builtin_amdgcn_mfma_f32_16x16x32_bf16(a, bfr[q], acc, 0, 0, 0);
    }
    // skip + exact GeLU, stage to LDS for coalesced write
#pragma unroll
    for (int r = 0; r < 4; ++r) {
      int m = 4 * g + r;
      int t = T0 + 16 * m + ln15;
      float y = acc[r] + Dh * su[t];
      float ge = 0.5f * y * (1.f + erff(y * 0.70710678118654752f));
      stg[wv][16 * m + ln15] = f2bf(ge);
    }
    uint2 v = *(uint2*)(&stg[wv][lane * 4]);
    *(uint2*)(X + (size_t)h * 8192 + (size_t)b * 4096 + T0 + lane * 4) = v;
  }
}

// ------- K3: GEMM (Y = Wb * X) + bias + fused GLU -> out f32 [2][2048][4096] -------
// Block tile: 64 a-rows (o=m0..m0+63) + 64 g-rows (o+2048), 128 cols, BK=64, double-buffered.
// 256 threads = 4 waves; wave (wv>>1, wv&1) owns 32a+32g rows x 64 cols = 16 mfma frags.
__global__ __launch_bounds__(256, 2) void gemm_glu_kernel(const uint16_t* __restrict__ Wb,
                                                          const uint16_t* __restrict__ X,
                                                          const float* __restrict__ bout,
                                                          float* __restrict__ out) {
  __shared__ char lds[65536];   // As[2][128][64]b16 @0, Bs[2][128 n][64 k]b16 @32768 (both XOR-swizzled)

  int tid = threadIdx.x;
  int lane = tid & 63;
  int wv = tid >> 6;

  // bijective XCD swizzle (nwg=2048 divisible by 8)
  int bid = blockIdx.x;
  int wg = (bid & 7) * 256 + (bid >> 3);
  int bm = wg >> 6, bn = wg & 63;
  int m0 = bm * 64, n0 = bn * 128;

  // ---- A staging coords: 4 chunks of 16B/thread; chunk c = i*256+tid -> row r=c>>3, byte (c&7)*16
  int arb = tid >> 3;           // + i*32
  int ab = (tid & 7) * 16;
  const char* Aglob[4];
  uint32_t AwAddr[4];
#pragma unroll
  for (int i = 0; i < 4; ++i) {
    int r = i * 32 + arb;       // 0..127 ; rows 0-63 = a (W rows m0+r), 64-127 = g (W rows 2048+m0+r-64)
    int o = (r < 64) ? (m0 + r) : (2048 + m0 + (r - 64));
    Aglob[i] = (const char*)Wb + (size_t)o * 4096 + ab;     // row stride 2048*2B
    AwAddr[i] = (uint32_t)(r * 128 + (ab ^ ((r & 7) << 4)));
  }
  // ---- B staging coords: thread covers 8 k-rows x 4 n; loads 8x uint2, writes 4x b128 transposed
  int n4 = (tid & 31) * 4;
  int kg = (tid >> 5) * 8;
  const char* Bglob = (const char*)X + ((size_t)kg * 8192 + (size_t)(n0 + n4)) * 2;
  uint32_t BwAddr[4];
#pragma unroll
  for (int no = 0; no < 4; ++no) {
    int n = n4 + no;
    BwAddr[no] = (uint32_t)(n * 128 + (((tid >> 5) * 16) ^ (swzB(n) << 4)));
  }

  f32x4 zero = {0.f, 0.f, 0.f, 0.f};
  f32x4 acc_a[2][4], acc_g[2][4];
#pragma unroll
  for (int mi = 0; mi < 2; ++mi)
#pragma unroll
    for (int ni = 0; ni < 4; ++ni) { acc_a[mi][ni] = zero; acc_g[mi][ni] = zero; }

  uint4 aR[4];
  uint2 bR[8];
  auto LOAD = [&](int t) {
    size_t koff = (size_t)t * 128;              // BK*2 bytes along k
#pragma unroll
    for (int i = 0; i < 4; ++i) aR[i] = *(const uint4*)(Aglob[i] + koff);
    size_t bko = (size_t)t * 64 * 16384;        // BK rows * 8192*2 bytes
#pragma unroll
    for (int i = 0; i < 8; ++i) bR[i] = *(const uint2*)(Bglob + bko + (size_t)i * 16384);
  };
  auto WRITE = [&](int buf) {
    char* A = lds + buf * 16384;
#pragma unroll
    for (int i = 0; i < 4; ++i) *(uint4*)(A + AwAddr[i]) = aR[i];
    char* Bb = lds + 32768 + buf * 16384;
    {
      uint4 q; q.x = pack_lo(bR[0].x, bR[1].x); q.y = pack_lo(bR[2].x, bR[3].x);
      q.z = pack_lo(bR[4].x, bR[5].x); q.w = pack_lo(bR[6].x, bR[7].x);
      *(uint4*)(Bb + BwAddr[0]) = q;
    }
    {
      uint4 q; q.x = pack_hi(bR[0].x, bR[1].x); q.y = pack_hi(bR[2].x, bR[3].x);
      q.z = pack_hi(bR[4].x, bR[5].x); q.w = pack_hi(bR[6].x, bR[7].x);
      *(uint4*)(Bb + BwAddr[1]) = q;
    }
    {
      uint4 q; q.x = pack_lo(bR[0].y, bR[1].y); q.y = pack_lo(bR[2].y, bR[3].y);
      q.z = pack_lo(bR[4].y, bR[5].y); q.w = pack_lo(bR[6].y, bR[7].y);
      *(uint4*)(Bb + BwAddr[2]) = q;
    }
    {
      uint4 q; q.x = pack_hi(bR[0].y, bR[1].y); q.y = pack_hi(bR[2].y, bR[3].y);
      q.z = pack_hi(bR[4].y, bR[5].y); q.w = pack_hi(bR[6].y, bR[7].y);
      *(uint4*)(Bb + BwAddr[3]) = q;
    }
  };

  LOAD(0);
  WRITE(0);
  __syncthreads();

  for (int t = 0; t < 32; ++t) {
    int cur = t & 1;
    if (t < 31) LOAD(t + 1);

    const char* A = lds + cur * 16384;
    const char* Bb = lds + 32768 + cur * 16384;
#pragma unroll
    for (int kk = 0; kk < 2; ++kk) {
      int kbyte = kk * 64 + ((lane >> 4) << 4);   // 2*(kk*32 + (lane>>4)*8)
      short8 fa[2], fg[2], fb[4];
#pragma unroll
      for (int mi = 0; mi < 2; ++mi) {
        int ra = (wv >> 1) * 32 + mi * 16 + (lane & 15);
        fa[mi] = *(const short8*)(A + ra * 128 + (kbyte ^ ((ra & 7) << 4)));
        int rg = 64 + ra;
        fg[mi] = *(const short8*)(A + rg * 128 + (kbyte ^ ((rg & 7) << 4)));
      }
#pragma unroll
      for (int ni = 0; ni < 4; ++ni) {
        int n = (wv & 1) * 64 + ni * 16 + (lane & 15);
        fb[ni] = *(const short8*)(Bb + n * 128 + (kbyte ^ (swzB(n) << 4)));
      }
#pragma unroll
      for (int mi = 0; mi < 2; ++mi)
#pragma unroll
        for (int ni = 0; ni < 4; ++ni) {
          acc_a[mi][ni] = __builtin_amdgcn_mfma_f32_16x16x32_bf16(fa[mi], fb[ni], acc_a[mi][ni], 0, 0, 0);
          acc_g[mi][ni] = __builtin_amdgcn_mfma_f32_16x16x32_bf16(fg[mi], fb[ni], acc_g[mi][ni], 0, 0, 0);
        }
    }

    if (t < 31) WRITE(cur ^ 1);
    __syncthreads();
  }

  // ---- epilogue: bias + GLU (a * sigmoid(g)), write f32 out [b][h][l]
  int colb = n0 + (wv & 1) * 64;
#pragma unroll
  for (int mi = 0; mi < 2; ++mi) {
    int ob = m0 + (wv >> 1) * 32 + mi * 16 + ((lane >> 4) << 2);
#pragma unroll
    for (int q = 0; q < 4; ++q) {
      int o = ob + q;
      float ba = bout[o];
      float bg = bout[o + 2048];
#pragma unroll
      for (int ni = 0; ni < 4; ++ni) {
        float av = acc_a[mi][ni][q] + ba;
        float gv = acc_g[mi][ni][q] + bg;
        float res = av / (1.f + expf(-gv));
        int n = colb + ni * 16 + (lane & 15);
        out[(size_t)(n >> 12) * 8388608 + (size_t)o * 4096 + (n & 4095)] = res;
      }
    }
  }
}

extern "C" void kernel_launch(void* const* d_in, const int* in_sizes, int n_in,
                              void* d_out, int out_size, void* d_ws, size_t ws_size,
                              hipStream_t stream) {
  const float* u    = (const float*)d_in[0];   // [2][2048][4096]
  const float* kern = (const float*)d_in[1];   // [1][2048][128]
  const float* D    = (const float*)d_in[2];   // [1][2048]
  const float* W    = (const float*)d_in[3];   // [4096][2048]
  const float* bo   = (const float*)d_in[4];   // [4096]
  float* out = (float*)d_out;                  // [2][2048][4096] f32

  uint16_t* Wb = (uint16_t*)d_ws;                                   // 16 MB
  uint16_t* X  = (uint16_t*)((char*)d_ws + (size_t)4096 * 2048 * 2); // 32 MB, [2048][8192]

  hipLaunchKernelGGL(cast_w_kernel,    dim3(4096), dim3(256), 0, stream, W, Wb);
  hipLaunchKernelGGL(conv_gelu_kernel, dim3(4096), dim3(256), 0, stream, u, kern, D, X);
  hipLaunchKernelGGL(gemm_glu_kernel,  dim3(2048), dim3(256), 0, stream, Wb, X, bo, out);
}

// Round 3
// 216.267 us; speedup vs baseline: 2.2330x; 1.3289x over previous
//
#include <hip/hip_runtime.h>
#include <stdint.h>

typedef short short8 __attribute__((ext_vector_type(8)));
typedef float f32x4 __attribute__((ext_vector_type(4)));

#define KLAM 0.003f
// B=2, H=2048, L=4096, Lk=128, N = B*L = 8192, M2 = 2H = 4096

__device__ __forceinline__ uint16_t f2bf(float f) {
  union { float f; uint32_t u; } v; v.f = f;
  uint32_t r = v.u + 0x7fffu + ((v.u >> 16) & 1u);  // RNE
  return (uint16_t)(r >> 16);
}
__device__ __forceinline__ uint32_t pack_lo(uint32_t a, uint32_t b) { return (a & 0xffffu) | (b << 16); }
__device__ __forceinline__ uint32_t pack_hi(uint32_t a, uint32_t b) { return (a >> 16) | (b & 0xffff0000u); }
__device__ __forceinline__ int swzB(int n) { return ((n & 7) ^ ((n >> 3) & 7)); }

typedef __attribute__((address_space(3))) uint32_t* lds_u32p;
typedef const __attribute__((address_space(1))) uint32_t* gbl_u32p;
__device__ __forceinline__ void gload16(const void* g, void* l) {
  __builtin_amdgcn_global_load_lds((gbl_u32p)g, (lds_u32p)l, 16, 0, 0);
}

// ---------------- K1: cast W_out (f32 [4096][2048]) -> bf16 ----------------
__global__ __launch_bounds__(256) void cast_w_kernel(const float* __restrict__ W,
                                                     uint16_t* __restrict__ Wb) {
  int i = (blockIdx.x * 256 + threadIdx.x) * 8;
  float4 f0 = *(const float4*)(W + i);
  float4 f1 = *(const float4*)(W + i + 4);
  uint4 q;
  q.x = (uint32_t)f2bf(f0.x) | ((uint32_t)f2bf(f0.y) << 16);
  q.y = (uint32_t)f2bf(f0.z) | ((uint32_t)f2bf(f0.w) << 16);
  q.z = (uint32_t)f2bf(f1.x) | ((uint32_t)f2bf(f1.y) << 16);
  q.w = (uint32_t)f2bf(f1.z) | ((uint32_t)f2bf(f1.w) << 16);
  *(uint4*)(Wb + i) = q;
}

// ------- K2: depthwise causal FIR (128 taps) via MFMA Toeplitz + u*D + exact GeLU -------
__global__ __launch_bounds__(256) void conv_gelu_kernel(const float* __restrict__ u,
                                                        const float* __restrict__ kern,
                                                        const float* __restrict__ D,
                                                        uint16_t* __restrict__ X) {
  __shared__ __align__(16) float su[4096];
  __shared__ __align__(16) uint16_t ubf[4256];
  __shared__ __align__(16) uint16_t kR[176];
  __shared__ __align__(16) uint16_t stg[4][256];

  int tid = threadIdx.x;
  int bh = blockIdx.x;
  int h = bh & 2047;
  int b = bh >> 11;
  int lane = tid & 63;
  int wv = tid >> 6;
  int ln15 = lane & 15;
  int g = lane >> 4;

  const float4* u4 = (const float4*)(u + (size_t)bh * 4096);
#pragma unroll
  for (int i = 0; i < 4; ++i) {
    float4 v = u4[i * 256 + tid];
    ((float4*)su)[i * 256 + tid] = v;
    uint2 p;
    p.x = (uint32_t)f2bf(v.x) | ((uint32_t)f2bf(v.y) << 16);
    p.y = (uint32_t)f2bf(v.z) | ((uint32_t)f2bf(v.w) << 16);
    *(uint2*)(ubf + 160 + (i * 256 + tid) * 4) = p;
  }
  if (tid < 40) { uint2 z; z.x = 0; z.y = 0; *(uint2*)(ubf + tid * 4) = z; }
  if (tid < 176) {
    int i = 159 - tid;
    uint16_t r = 0;
    if (i >= 0 && i < 128) {
      float kv = kern[h * 128 + i];
      float a = fabsf(kv) - KLAM;
      float s = (a > 0.f) ? (kv > 0.f ? a : -a) : 0.f;
      r = f2bf(s);
    }
    kR[tid] = r;
  }
  __syncthreads();

  float Dh = D[h];

  short8 bfr[5];
#pragma unroll
  for (int q = 0; q < 5; ++q) {
    int z0 = 143 - 32 * q - ln15 + 8 * g;
    union { short8 v; uint16_t s[8]; } t;
#pragma unroll
    for (int e = 0; e < 8; ++e) t.s[e] = kR[z0 + e];
    bfr[q] = t.v;
  }

#pragma unroll
  for (int it = 0; it < 4; ++it) {
    int T0 = (wv * 4 + it) * 256;
    f32x4 acc = {0.f, 0.f, 0.f, 0.f};
#pragma unroll
    for (int q = 0; q < 5; ++q) {
      const short8 a = *(const short8*)(ubf + 160 + T0 + 16 * ln15 - 16 - 32 * q + 8 * g);
      acc = __builtin_amdgcn_mfma_f32_16x16x32_bf16(a, bfr[q], acc, 0, 0, 0);
    }
#pragma unroll
    for (int r = 0; r < 4; ++r) {
      int m = 4 * g + r;
      int t = T0 + 16 * m + ln15;
      float y = acc[r] + Dh * su[t];
      float ge = 0.5f * y * (1.f + erff(y * 0.70710678118654752f));
      stg[wv][16 * m + ln15] = f2bf(ge);
    }
    uint2 v = *(uint2*)(&stg[wv][lane * 4]);
    *(uint2*)(X + (size_t)h * 8192 + (size_t)b * 4096 + T0 + lane * 4) = v;
  }
}

// ------- K2b: transpose X [2048][8192] -> XT [8192][2048] (bf16) -------
__global__ __launch_bounds__(256) void transpose_kernel(const uint16_t* __restrict__ X,
                                                        uint16_t* __restrict__ XT) {
  __shared__ uint16_t t[64][66];
  int tid = threadIdx.x;
  int bn = blockIdx.x & 127;   // n-tile
  int bk = blockIdx.x >> 7;    // k-tile
  int n0 = bn << 6, k0 = bk << 6;
  int cr = tid >> 3;           // 0..31
  int cc = (tid & 7) * 8;      // 0..56
#pragma unroll
  for (int p = 0; p < 2; ++p) {
    int kr = p * 32 + cr;
    uint4 v = *(const uint4*)(X + (size_t)(k0 + kr) * 8192 + n0 + cc);
    const uint16_t* s = (const uint16_t*)&v;
#pragma unroll
    for (int e = 0; e < 8; ++e) t[cc + e][kr] = s[e];
  }
  __syncthreads();
#pragma unroll
  for (int p = 0; p < 2; ++p) {
    int nl = p * 32 + cr;
    uint16_t d[8];
#pragma unroll
    for (int e = 0; e < 8; ++e) d[e] = t[nl][cc + e];
    *(uint4*)(XT + (size_t)(n0 + nl) * 2048 + k0 + cc) = *(uint4*)d;
  }
}

// ------- K3 v2: GEMM via global_load_lds staging (m97 structure) + fused GLU -------
// Tile: 64 a-rows + 64 g-rows (LDS rows 0-127), 128 cols, BK=64, double-buffered 64 KB.
// LDS linear dest + inverse-swizzled global source + swizzled ds_read (XOR (r&7)<<4).
__global__ __launch_bounds__(256, 2) void gemm_glu_v2(const uint16_t* __restrict__ Wb,
                                                      const uint16_t* __restrict__ XT,
                                                      const float* __restrict__ bout,
                                                      float* __restrict__ out) {
  __shared__ __align__(16) char lds[65536];  // A[2][128][64]bf16 @0, B[2][128][64] @32768

  int tid = threadIdx.x;
  int lane = tid & 63;
  int wv = tid >> 6;
  int ln15 = lane & 15, g = lane >> 4;

  int bid = blockIdx.x;
  int wg = (bid & 7) * 256 + (bid >> 3);   // bijective XCD swizzle (2048 % 8 == 0)
  int bm = wg >> 6, bn = wg & 63;
  int m0 = bm * 64, n0 = bn * 128;

  // staging: 16 chunks (8 rows x 128B each) per operand; wave wv owns chunks wv*4..wv*4+3
  int lr = lane >> 3;                       // row within chunk
  int sb = (((lane & 7) ^ lr) << 4);        // inverse-swizzled byte within row
  const char* asrc[4];
  const char* bsrc[4];
#pragma unroll
  for (int i = 0; i < 4; ++i) {
    int c = wv * 4 + i;
    int r = c * 8 + lr;                     // LDS row 0..127
    int o = (r < 64) ? (m0 + r) : (2048 + m0 + r - 64);
    asrc[i] = (const char*)Wb + (size_t)o * 4096 + sb;
    bsrc[i] = (const char*)XT + (size_t)(n0 + r) * 4096 + sb;
  }

  f32x4 zero = {0.f, 0.f, 0.f, 0.f};
  f32x4 acc_a[2][4], acc_g[2][4];
#pragma unroll
  for (int mi = 0; mi < 2; ++mi)
#pragma unroll
    for (int ni = 0; ni < 4; ++ni) { acc_a[mi][ni] = zero; acc_g[mi][ni] = zero; }

  auto STAGE = [&](int buf, int t) {
    size_t koff = (size_t)t * 128;
    char* la = lds + buf * 16384 + wv * 4096;
    char* lb = lds + 32768 + buf * 16384 + wv * 4096;
#pragma unroll
    for (int i = 0; i < 4; ++i) {
      gload16(asrc[i] + koff, la + i * 1024);
      gload16(bsrc[i] + koff, lb + i * 1024);
    }
  };

  STAGE(0, 0);
  __syncthreads();

  int buf = 0;
  for (int t = 0; t < 32; ++t) {
    if (t < 31) STAGE(buf ^ 1, t + 1);

    const char* A = lds + buf * 16384;
    const char* Bb = lds + 32768 + buf * 16384;
#pragma unroll
    for (int kk = 0; kk < 2; ++kk) {
      int kbyte = kk * 64 + g * 16;
      short8 fa[2], fg[2], fb[4];
#pragma unroll
      for (int mi = 0; mi < 2; ++mi) {
        int ra = (wv >> 1) * 32 + mi * 16 + ln15;
        fa[mi] = *(const short8*)(A + ra * 128 + (kbyte ^ ((ra & 7) << 4)));
        int rg = 64 + ra;
        fg[mi] = *(const short8*)(A + rg * 128 + (kbyte ^ ((rg & 7) << 4)));
      }
#pragma unroll
      for (int ni = 0; ni < 4; ++ni) {
        int n = (wv & 1) * 64 + ni * 16 + ln15;
        fb[ni] = *(const short8*)(Bb + n * 128 + (kbyte ^ ((n & 7) << 4)));
      }
#pragma unroll
      for (int mi = 0; mi < 2; ++mi)
#pragma unroll
        for (int ni = 0; ni < 4; ++ni) {
          acc_a[mi][ni] = __builtin_amdgcn_mfma_f32_16x16x32_bf16(fa[mi], fb[ni], acc_a[mi][ni], 0, 0, 0);
          acc_g[mi][ni] = __builtin_amdgcn_mfma_f32_16x16x32_bf16(fg[mi], fb[ni], acc_g[mi][ni], 0, 0, 0);
        }
    }

    __syncthreads();
    buf ^= 1;
  }

  int colb = n0 + (wv & 1) * 64;
#pragma unroll
  for (int mi = 0; mi < 2; ++mi) {
    int ob = m0 + (wv >> 1) * 32 + mi * 16 + ((lane >> 4) << 2);
#pragma unroll
    for (int q = 0; q < 4; ++q) {
      int o = ob + q;
      float ba = bout[o];
      float bg = bout[o + 2048];
#pragma unroll
      for (int ni = 0; ni < 4; ++ni) {
        float av = acc_a[mi][ni][q] + ba;
        float gv = acc_g[mi][ni][q] + bg;
        float res = av / (1.f + expf(-gv));
        int n = colb + ni * 16 + ln15;
        out[(size_t)(n >> 12) * 8388608 + (size_t)o * 4096 + (n & 4095)] = res;
      }
    }
  }
}

// ------- K3 v1 (fallback if ws too small for XT): reg-staged GEMM from X [k][n] -------
__global__ __launch_bounds__(256, 2) void gemm_glu_v1(const uint16_t* __restrict__ Wb,
                                                      const uint16_t* __restrict__ X,
                                                      const float* __restrict__ bout,
                                                      float* __restrict__ out) {
  __shared__ char lds[65536];

  int tid = threadIdx.x;
  int lane = tid & 63;
  int wv = tid >> 6;

  int bid = blockIdx.x;
  int wg = (bid & 7) * 256 + (bid >> 3);
  int bm = wg >> 6, bn = wg & 63;
  int m0 = bm * 64, n0 = bn * 128;

  int arb = tid >> 3;
  int ab = (tid & 7) * 16;
  const char* Aglob[4];
  uint32_t AwAddr[4];
#pragma unroll
  for (int i = 0; i < 4; ++i) {
    int r = i * 32 + arb;
    int o = (r < 64) ? (m0 + r) : (2048 + m0 + (r - 64));
    Aglob[i] = (const char*)Wb + (size_t)o * 4096 + ab;
    AwAddr[i] = (uint32_t)(r * 128 + (ab ^ ((r & 7) << 4)));
  }
  int n4 = (tid & 31) * 4;
  int kg = (tid >> 5) * 8;
  const char* Bglob = (const char*)X + ((size_t)kg * 8192 + (size_t)(n0 + n4)) * 2;
  uint32_t BwAddr[4];
#pragma unroll
  for (int no = 0; no < 4; ++no) {
    int n = n4 + no;
    BwAddr[no] = (uint32_t)(n * 128 + (((tid >> 5) * 16) ^ (swzB(n) << 4)));
  }

  f32x4 zero = {0.f, 0.f, 0.f, 0.f};
  f32x4 acc_a[2][4], acc_g[2][4];
#pragma unroll
  for (int mi = 0; mi < 2; ++mi)
#pragma unroll
    for (int ni = 0; ni < 4; ++ni) { acc_a[mi][ni] = zero; acc_g[mi][ni] = zero; }

  uint4 aR[4];
  uint2 bR[8];
  auto LOAD = [&](int t) {
    size_t koff = (size_t)t * 128;
#pragma unroll
    for (int i = 0; i < 4; ++i) aR[i] = *(const uint4*)(Aglob[i] + koff);
    size_t bko = (size_t)t * 64 * 16384;
#pragma unroll
    for (int i = 0; i < 8; ++i) bR[i] = *(const uint2*)(Bglob + bko + (size_t)i * 16384);
  };
  auto WRITE = [&](int buf) {
    char* A = lds + buf * 16384;
#pragma unroll
    for (int i = 0; i < 4; ++i) *(uint4*)(A + AwAddr[i]) = aR[i];
    char* Bb = lds + 32768 + buf * 16384;
    {
      uint4 q; q.x = pack_lo(bR[0].x, bR[1].x); q.y = pack_lo(bR[2].x, bR[3].x);
      q.z = pack_lo(bR[4].x, bR[5].x); q.w = pack_lo(bR[6].x, bR[7].x);
      *(uint4*)(Bb + BwAddr[0]) = q;
    }
    {
      uint4 q; q.x = pack_hi(bR[0].x, bR[1].x); q.y = pack_hi(bR[2].x, bR[3].x);
      q.z = pack_hi(bR[4].x, bR[5].x); q.w = pack_hi(bR[6].x, bR[7].x);
      *(uint4*)(Bb + BwAddr[1]) = q;
    }
    {
      uint4 q; q.x = pack_lo(bR[0].y, bR[1].y); q.y = pack_lo(bR[2].y, bR[3].y);
      q.z = pack_lo(bR[4].y, bR[5].y); q.w = pack_lo(bR[6].y, bR[7].y);
      *(uint4*)(Bb + BwAddr[2]) = q;
    }
    {
      uint4 q; q.x = pack_hi(bR[0].y, bR[1].y); q.y = pack_hi(bR[2].y, bR[3].y);
      q.z = pack_hi(bR[4].y, bR[5].y); q.w = pack_hi(bR[6].y, bR[7].y);
      *(uint4*)(Bb + BwAddr[3]) = q;
    }
  };

  LOAD(0);
  WRITE(0);
  __syncthreads();

  for (int t = 0; t < 32; ++t) {
    int cur = t & 1;
    if (t < 31) LOAD(t + 1);

    const char* A = lds + cur * 16384;
    const char* Bb = lds + 32768 + cur * 16384;
#pragma unroll
    for (int kk = 0; kk < 2; ++kk) {
      int kbyte = kk * 64 + ((lane >> 4) << 4);
      short8 fa[2], fg[2], fb[4];
#pragma unroll
      for (int mi = 0; mi < 2; ++mi) {
        int ra = (wv >> 1) * 32 + mi * 16 + (lane & 15);
        fa[mi] = *(const short8*)(A + ra * 128 + (kbyte ^ ((ra & 7) << 4)));
        int rg = 64 + ra;
        fg[mi] = *(const short8*)(A + rg * 128 + (kbyte ^ ((rg & 7) << 4)));
      }
#pragma unroll
      for (int ni = 0; ni < 4; ++ni) {
        int n = (wv & 1) * 64 + ni * 16 + (lane & 15);
        fb[ni] = *(const short8*)(Bb + n * 128 + (kbyte ^ (swzB(n) << 4)));
      }
#pragma unroll
      for (int mi = 0; mi < 2; ++mi)
#pragma unroll
        for (int ni = 0; ni < 4; ++ni) {
          acc_a[mi][ni] = __builtin_amdgcn_mfma_f32_16x16x32_bf16(fa[mi], fb[ni], acc_a[mi][ni], 0, 0, 0);
          acc_g[mi][ni] = __builtin_amdgcn_mfma_f32_16x16x32_bf16(fg[mi], fb[ni], acc_g[mi][ni], 0, 0, 0);
        }
    }

    if (t < 31) WRITE(cur ^ 1);
    __syncthreads();
  }

  int colb = n0 + (wv & 1) * 64;
#pragma unroll
  for (int mi = 0; mi < 2; ++mi) {
    int ob = m0 + (wv >> 1) * 32 + mi * 16 + ((lane >> 4) << 2);
#pragma unroll
    for (int q = 0; q < 4; ++q) {
      int o = ob + q;
      float ba = bout[o];
      float bg = bout[o + 2048];
#pragma unroll
      for (int ni = 0; ni < 4; ++ni) {
        float av = acc_a[mi][ni][q] + ba;
        float gv = acc_g[mi][ni][q] + bg;
        float res = av / (1.f + expf(-gv));
        int n = colb + ni * 16 + (lane & 15);
        out[(size_t)(n >> 12) * 8388608 + (size_t)o * 4096 + (n & 4095)] = res;
      }
    }
  }
}

extern "C" void kernel_launch(void* const* d_in, const int* in_sizes, int n_in,
                              void* d_out, int out_size, void* d_ws, size_t ws_size,
                              hipStream_t stream) {
  const float* u    = (const float*)d_in[0];
  const float* kern = (const float*)d_in[1];
  const float* D    = (const float*)d_in[2];
  const float* W    = (const float*)d_in[3];
  const float* bo   = (const float*)d_in[4];
  float* out = (float*)d_out;

  uint16_t* Wb = (uint16_t*)d_ws;                                      // 16 MB @ 0
  uint16_t* X  = (uint16_t*)((char*)d_ws + (size_t)16 * 1024 * 1024);  // 32 MB @ 16M
  uint16_t* XT = (uint16_t*)((char*)d_ws + (size_t)48 * 1024 * 1024);  // 32 MB @ 48M

  hipLaunchKernelGGL(cast_w_kernel,    dim3(4096), dim3(256), 0, stream, W, Wb);
  hipLaunchKernelGGL(conv_gelu_kernel, dim3(4096), dim3(256), 0, stream, u, kern, D, X);
  if (ws_size >= (size_t)80 * 1024 * 1024) {
    hipLaunchKernelGGL(transpose_kernel, dim3(4096), dim3(256), 0, stream, X, XT);
    hipLaunchKernelGGL(gemm_glu_v2,      dim3(2048), dim3(256), 0, stream, Wb, XT, bo, out);
  } else {
    hipLaunchKernelGGL(gemm_glu_v1,      dim3(2048), dim3(256), 0, stream, Wb, X, bo, out);
  }
}

// Round 4
// 184.184 us; speedup vs baseline: 2.6220x; 1.1742x over previous
//
#include <hip/hip_runtime.h>
#include <stdint.h>

typedef short short8 __attribute__((ext_vector_type(8)));
typedef float f32x4 __attribute__((ext_vector_type(4)));

#define KLAM 0.003f
// B=2, H=2048, L=4096, Lk=128, N = B*L = 8192, M2 = 2H = 4096

__device__ __forceinline__ uint16_t f2bf(float f) {
  union { float f; uint32_t u; } v; v.f = f;
  uint32_t r = v.u + 0x7fffu + ((v.u >> 16) & 1u);  // RNE
  return (uint16_t)(r >> 16);
}
__device__ __forceinline__ uint32_t pack_lo(uint32_t a, uint32_t b) { return (a & 0xffffu) | (b << 16); }
__device__ __forceinline__ uint32_t pack_hi(uint32_t a, uint32_t b) { return (a >> 16) | (b & 0xffff0000u); }
__device__ __forceinline__ int swzB(int n) { return ((n & 7) ^ ((n >> 3) & 7)); }

typedef __attribute__((address_space(3))) uint32_t* lds_u32p;
typedef const __attribute__((address_space(1))) uint32_t* gbl_u32p;
__device__ __forceinline__ void gload16(const void* g, void* l) {
  __builtin_amdgcn_global_load_lds((gbl_u32p)g, (lds_u32p)l, 16, 0, 0);
}

// ---------------- K1: cast W_out (f32 [4096][2048]) -> bf16 ----------------
__global__ __launch_bounds__(256) void cast_w_kernel(const float* __restrict__ W,
                                                     uint16_t* __restrict__ Wb) {
  int i = (blockIdx.x * 256 + threadIdx.x) * 8;
  float4 f0 = *(const float4*)(W + i);
  float4 f1 = *(const float4*)(W + i + 4);
  uint4 q;
  q.x = (uint32_t)f2bf(f0.x) | ((uint32_t)f2bf(f0.y) << 16);
  q.y = (uint32_t)f2bf(f0.z) | ((uint32_t)f2bf(f0.w) << 16);
  q.z = (uint32_t)f2bf(f1.x) | ((uint32_t)f2bf(f1.y) << 16);
  q.w = (uint32_t)f2bf(f1.z) | ((uint32_t)f2bf(f1.w) << 16);
  *(uint4*)(Wb + i) = q;
}

// ------- K2: depthwise causal FIR (128 taps) via MFMA Toeplitz + u*D + exact GeLU -------
__global__ __launch_bounds__(256) void conv_gelu_kernel(const float* __restrict__ u,
                                                        const float* __restrict__ kern,
                                                        const float* __restrict__ D,
                                                        uint16_t* __restrict__ X) {
  __shared__ __align__(16) float su[4096];
  __shared__ __align__(16) uint16_t ubf[4256];
  __shared__ __align__(16) uint16_t kR[176];
  __shared__ __align__(16) uint16_t stg[4][256];

  int tid = threadIdx.x;
  int bh = blockIdx.x;
  int h = bh & 2047;
  int b = bh >> 11;
  int lane = tid & 63;
  int wv = tid >> 6;
  int ln15 = lane & 15;
  int g = lane >> 4;

  const float4* u4 = (const float4*)(u + (size_t)bh * 4096);
#pragma unroll
  for (int i = 0; i < 4; ++i) {
    float4 v = u4[i * 256 + tid];
    ((float4*)su)[i * 256 + tid] = v;
    uint2 p;
    p.x = (uint32_t)f2bf(v.x) | ((uint32_t)f2bf(v.y) << 16);
    p.y = (uint32_t)f2bf(v.z) | ((uint32_t)f2bf(v.w) << 16);
    *(uint2*)(ubf + 160 + (i * 256 + tid) * 4) = p;
  }
  if (tid < 40) { uint2 z; z.x = 0; z.y = 0; *(uint2*)(ubf + tid * 4) = z; }
  if (tid < 176) {
    int i = 159 - tid;
    uint16_t r = 0;
    if (i >= 0 && i < 128) {
      float kv = kern[h * 128 + i];
      float a = fabsf(kv) - KLAM;
      float s = (a > 0.f) ? (kv > 0.f ? a : -a) : 0.f;
      r = f2bf(s);
    }
    kR[tid] = r;
  }
  __syncthreads();

  float Dh = D[h];

  short8 bfr[5];
#pragma unroll
  for (int q = 0; q < 5; ++q) {
    int z0 = 143 - 32 * q - ln15 + 8 * g;
    union { short8 v; uint16_t s[8]; } t;
#pragma unroll
    for (int e = 0; e < 8; ++e) t.s[e] = kR[z0 + e];
    bfr[q] = t.v;
  }

#pragma unroll
  for (int it = 0; it < 4; ++it) {
    int T0 = (wv * 4 + it) * 256;
    f32x4 acc = {0.f, 0.f, 0.f, 0.f};
#pragma unroll
    for (int q = 0; q < 5; ++q) {
      const short8 a = *(const short8*)(ubf + 160 + T0 + 16 * ln15 - 16 - 32 * q + 8 * g);
      acc = __builtin_amdgcn_mfma_f32_16x16x32_bf16(a, bfr[q], acc, 0, 0, 0);
    }
#pragma unroll
    for (int r = 0; r < 4; ++r) {
      int m = 4 * g + r;
      int t = T0 + 16 * m + ln15;
      float y = acc[r] + Dh * su[t];
      float ge = 0.5f * y * (1.f + erff(y * 0.70710678118654752f));
      stg[wv][16 * m + ln15] = f2bf(ge);
    }
    uint2 v = *(uint2*)(&stg[wv][lane * 4]);
    *(uint2*)(X + (size_t)h * 8192 + (size_t)b * 4096 + T0 + lane * 4) = v;
  }
}

// ------- K2b: transpose X [2048][8192] -> XT [8192][2048] (bf16) -------
__global__ __launch_bounds__(256) void transpose_kernel(const uint16_t* __restrict__ X,
                                                        uint16_t* __restrict__ XT) {
  __shared__ uint16_t t[64][66];
  int tid = threadIdx.x;
  int bn = blockIdx.x & 127;   // n-tile
  int bk = blockIdx.x >> 7;    // k-tile
  int n0 = bn << 6, k0 = bk << 6;
  int cr = tid >> 3;           // 0..31
  int cc = (tid & 7) * 8;      // 0..56
#pragma unroll
  for (int p = 0; p < 2; ++p) {
    int kr = p * 32 + cr;
    uint4 v = *(const uint4*)(X + (size_t)(k0 + kr) * 8192 + n0 + cc);
    const uint16_t* s = (const uint16_t*)&v;
#pragma unroll
    for (int e = 0; e < 8; ++e) t[cc + e][kr] = s[e];
  }
  __syncthreads();
#pragma unroll
  for (int p = 0; p < 2; ++p) {
    int nl = p * 32 + cr;
    uint16_t d[8];
#pragma unroll
    for (int e = 0; e < 8; ++e) d[e] = t[nl][cc + e];
    *(uint4*)(XT + (size_t)(n0 + nl) * 2048 + k0 + cc) = *(uint4*)d;
  }
}

// ------- K3 v3: 256x256 8-phase-style GEMM + fused GLU (T2+T3+T4+T5) -------
// BM=256 (128 a-rows + 128 g-rows), BN=256, BK=64, 512 thr / 8 waves, LDS 128 KB dbuf.
// Per K-tile 4 phases x 16 MFMA; 1 half-tile staged per phase; vmcnt(6) once per tile.
__global__ __launch_bounds__(512, 2) void gemm_glu_v3(const uint16_t* __restrict__ Wb,
                                                      const uint16_t* __restrict__ XT,
                                                      const float* __restrict__ bout,
                                                      float* __restrict__ out) {
  __shared__ __align__(16) char lds[131072];  // A[2][256][64]bf16 @0, B[2][256][64] @65536

  int tid = threadIdx.x;
  int lane = tid & 63;
  int wv = tid >> 6;          // 0..7
  int wr = wv >> 2;           // 0..1  (M half)
  int wc = wv & 3;            // 0..3  (N quarter)
  int ln15 = lane & 15;
  int g16 = lane >> 4;        // 0..3

  // bijective XCD swizzle (512 % 8 == 0)
  int bid = blockIdx.x;
  int wg = (bid & 7) * 64 + (bid >> 3);
  int bm = wg >> 5, bn = wg & 31;       // 16 x 32
  int mo0 = bm * 128, n0 = bn * 256;

  // ---- staging source pointers (pre-swizzled global, linear LDS dest) ----
  int lr8 = lane >> 3;                        // 0..7
  int sb = (((lane & 7) ^ lr8) << 4);
  const char* wbB = (const char*)Wb;
  const char* xtB = (const char*)XT;
  const char* srcAA = wbB + (size_t)(mo0 + wv * 16 + lr8) * 4096 + sb;
  const char* srcAG = wbB + (size_t)(2048 + mo0 + wv * 16 + lr8) * 4096 + sb;
  const char* srcBL = xtB + (size_t)(n0 + wv * 16 + lr8) * 4096 + sb;
  const char* srcBH = xtB + (size_t)(n0 + 128 + wv * 16 + lr8) * 4096 + sb;
  // LDS dest (wave-uniform): chunk c = wv*2+i of each 16KB half
  uint32_t ldW = wv * 2048;

  auto stageAA = [&](int buf, int t) {
    size_t ko = (size_t)t * 128;
    char* d = lds + buf * 32768 + ldW;
    gload16(srcAA + ko, d);
    gload16(srcAA + ko + 32768, d + 1024);
  };
  auto stageAG = [&](int buf, int t) {
    size_t ko = (size_t)t * 128;
    char* d = lds + buf * 32768 + 16384 + ldW;
    gload16(srcAG + ko, d);
    gload16(srcAG + ko + 32768, d + 1024);
  };
  auto stageBL = [&](int buf, int t) {
    size_t ko = (size_t)t * 128;
    char* d = lds + 65536 + buf * 32768 + ldW;
    gload16(srcBL + ko, d);
    gload16(srcBL + ko + 32768, d + 1024);
  };
  auto stageBH = [&](int buf, int t) {
    size_t ko = (size_t)t * 128;
    char* d = lds + 65536 + buf * 32768 + 16384 + ldW;
    gload16(srcBH + ko, d);
    gload16(srcBH + ko + 32768, d + 1024);
  };

  f32x4 zero = {0.f, 0.f, 0.f, 0.f};
  f32x4 acc_a[4][4], acc_g[4][4];
#pragma unroll
  for (int mi = 0; mi < 4; ++mi)
#pragma unroll
    for (int ni = 0; ni < 4; ++ni) { acc_a[mi][ni] = zero; acc_g[mi][ni] = zero; }

  // ---- prologue: tile0 full + tile1 minus BHI ----
  stageAA(0, 0); stageBL(0, 0); stageAG(0, 0); stageBH(0, 0);
  stageAA(1, 1); stageBL(1, 1); stageAG(1, 1);
  asm volatile("s_waitcnt vmcnt(6)" ::: "memory");
  __builtin_amdgcn_s_barrier();

  short8 fa[4][2], fg[4][2], fb[4][2];

  for (int t = 0; t < 32; ++t) {
    int cur = t & 1;
    const char* A = lds + cur * 32768;
    const char* Bb = lds + 65536 + cur * 32768;

    // ---- P1: read a-frags + b-frags(ni 0,1); stage BHI(t+1)->other buf; MFMA a x n-lo
#pragma unroll
    for (int mi = 0; mi < 4; ++mi) {
      int ra = wr * 64 + mi * 16 + ln15;
      int sw = (ra & 7) << 4;
#pragma unroll
      for (int kk = 0; kk < 2; ++kk)
        fa[mi][kk] = *(const short8*)(A + ra * 128 + ((kk * 64 + g16 * 16) ^ sw));
    }
#pragma unroll
    for (int ni = 0; ni < 2; ++ni) {
      int n = wc * 64 + ni * 16 + ln15;
      int sw = (n & 7) << 4;
#pragma unroll
      for (int kk = 0; kk < 2; ++kk)
        fb[ni][kk] = *(const short8*)(Bb + n * 128 + ((kk * 64 + g16 * 16) ^ sw));
    }
    if (t < 31) stageBH(cur ^ 1, t + 1);
    __builtin_amdgcn_s_barrier();
    asm volatile("s_waitcnt lgkmcnt(0)" ::: "memory");
    __builtin_amdgcn_s_setprio(1);
#pragma unroll
    for (int mi = 0; mi < 4; ++mi)
#pragma unroll
      for (int ni = 0; ni < 2; ++ni)
#pragma unroll
        for (int kk = 0; kk < 2; ++kk)
          acc_a[mi][ni] = __builtin_amdgcn_mfma_f32_16x16x32_bf16(fa[mi][kk], fb[ni][kk], acc_a[mi][ni], 0, 0, 0);
    __builtin_amdgcn_s_setprio(0);
    __builtin_amdgcn_s_barrier();

    // ---- P2: read b-frags(ni 2,3); stage AA(t+2)->cur; MFMA a x n-hi
#pragma unroll
    for (int ni = 2; ni < 4; ++ni) {
      int n = wc * 64 + ni * 16 + ln15;
      int sw = (n & 7) << 4;
#pragma unroll
      for (int kk = 0; kk < 2; ++kk)
        fb[ni][kk] = *(const short8*)(Bb + n * 128 + ((kk * 64 + g16 * 16) ^ sw));
    }
    if (t < 30) stageAA(cur, t + 2);
    __builtin_amdgcn_s_barrier();
    asm volatile("s_waitcnt lgkmcnt(0)" ::: "memory");
    __builtin_amdgcn_s_setprio(1);
#pragma unroll
    for (int mi = 0; mi < 4; ++mi)
#pragma unroll
      for (int ni = 2; ni < 4; ++ni)
#pragma unroll
        for (int kk = 0; kk < 2; ++kk)
          acc_a[mi][ni] = __builtin_amdgcn_mfma_f32_16x16x32_bf16(fa[mi][kk], fb[ni][kk], acc_a[mi][ni], 0, 0, 0);
    __builtin_amdgcn_s_setprio(0);
    __builtin_amdgcn_s_barrier();

    // ---- P3: read g-frags; stage BLO(t+2)->cur; MFMA g x n-lo
#pragma unroll
    for (int mi = 0; mi < 4; ++mi) {
      int rg = 128 + wr * 64 + mi * 16 + ln15;
      int sw = (rg & 7) << 4;
#pragma unroll
      for (int kk = 0; kk < 2; ++kk)
        fg[mi][kk] = *(const short8*)(A + rg * 128 + ((kk * 64 + g16 * 16) ^ sw));
    }
    if (t < 30) stageBL(cur, t + 2);
    __builtin_amdgcn_s_barrier();
    asm volatile("s_waitcnt lgkmcnt(0)" ::: "memory");
    __builtin_amdgcn_s_setprio(1);
#pragma unroll
    for (int mi = 0; mi < 4; ++mi)
#pragma unroll
      for (int ni = 0; ni < 2; ++ni)
#pragma unroll
        for (int kk = 0; kk < 2; ++kk)
          acc_g[mi][ni] = __builtin_amdgcn_mfma_f32_16x16x32_bf16(fg[mi][kk], fb[ni][kk], acc_g[mi][ni], 0, 0, 0);
    __builtin_amdgcn_s_setprio(0);
    __builtin_amdgcn_s_barrier();

    // ---- P4: stage AG(t+2)->cur; vmcnt; MFMA g x n-hi
    if (t < 30) stageAG(cur, t + 2);
    if (t < 30) { asm volatile("s_waitcnt vmcnt(6)" ::: "memory"); }
    else        { asm volatile("s_waitcnt vmcnt(0)" ::: "memory"); }
    __builtin_amdgcn_s_barrier();
    __builtin_amdgcn_s_setprio(1);
#pragma unroll
    for (int mi = 0; mi < 4; ++mi)
#pragma unroll
      for (int ni = 2; ni < 4; ++ni)
#pragma unroll
        for (int kk = 0; kk < 2; ++kk)
          acc_g[mi][ni] = __builtin_amdgcn_mfma_f32_16x16x32_bf16(fg[mi][kk], fb[ni][kk], acc_g[mi][ni], 0, 0, 0);
    __builtin_amdgcn_s_setprio(0);
    __builtin_amdgcn_s_barrier();
  }

  // ---- epilogue: bias + GLU (a * sigmoid(g)), write f32 out [b][o][l]
#pragma unroll
  for (int mi = 0; mi < 4; ++mi) {
    int ob = mo0 + wr * 64 + mi * 16 + g16 * 4;
    float4 ba4 = *(const float4*)(bout + ob);
    float4 bg4 = *(const float4*)(bout + ob + 2048);
    const float* bap = (const float*)&ba4;
    const float* bgp = (const float*)&bg4;
#pragma unroll
    for (int q = 0; q < 4; ++q) {
      int o = ob + q;
#pragma unroll
      for (int ni = 0; ni < 4; ++ni) {
        float av = acc_a[mi][ni][q] + bap[q];
        float gv = acc_g[mi][ni][q] + bgp[q];
        float res = av / (1.f + expf(-gv));
        int n = n0 + wc * 64 + ni * 16 + ln15;
        out[(size_t)(n >> 12) * 8388608 + (size_t)o * 4096 + (n & 4095)] = res;
      }
    }
  }
}

// ------- K3 v1 (fallback if ws too small for XT): reg-staged GEMM from X [k][n] -------
__global__ __launch_bounds__(256, 2) void gemm_glu_v1(const uint16_t* __restrict__ Wb,
                                                      const uint16_t* __restrict__ X,
                                                      const float* __restrict__ bout,
                                                      float* __restrict__ out) {
  __shared__ char lds[65536];

  int tid = threadIdx.x;
  int lane = tid & 63;
  int wv = tid >> 6;

  int bid = blockIdx.x;
  int wg = (bid & 7) * 256 + (bid >> 3);
  int bm = wg >> 6, bn = wg & 63;
  int m0 = bm * 64, n0 = bn * 128;

  int arb = tid >> 3;
  int ab = (tid & 7) * 16;
  const char* Aglob[4];
  uint32_t AwAddr[4];
#pragma unroll
  for (int i = 0; i < 4; ++i) {
    int r = i * 32 + arb;
    int o = (r < 64) ? (m0 + r) : (2048 + m0 + (r - 64));
    Aglob[i] = (const char*)Wb + (size_t)o * 4096 + ab;
    AwAddr[i] = (uint32_t)(r * 128 + (ab ^ ((r & 7) << 4)));
  }
  int n4 = (tid & 31) * 4;
  int kg = (tid >> 5) * 8;
  const char* Bglob = (const char*)X + ((size_t)kg * 8192 + (size_t)(n0 + n4)) * 2;
  uint32_t BwAddr[4];
#pragma unroll
  for (int no = 0; no < 4; ++no) {
    int n = n4 + no;
    BwAddr[no] = (uint32_t)(n * 128 + (((tid >> 5) * 16) ^ (swzB(n) << 4)));
  }

  f32x4 zero = {0.f, 0.f, 0.f, 0.f};
  f32x4 acc_a[2][4], acc_g[2][4];
#pragma unroll
  for (int mi = 0; mi < 2; ++mi)
#pragma unroll
    for (int ni = 0; ni < 4; ++ni) { acc_a[mi][ni] = zero; acc_g[mi][ni] = zero; }

  uint4 aR[4];
  uint2 bR[8];
  auto LOAD = [&](int t) {
    size_t koff = (size_t)t * 128;
#pragma unroll
    for (int i = 0; i < 4; ++i) aR[i] = *(const uint4*)(Aglob[i] + koff);
    size_t bko = (size_t)t * 64 * 16384;
#pragma unroll
    for (int i = 0; i < 8; ++i) bR[i] = *(const uint2*)(Bglob + bko + (size_t)i * 16384);
  };
  auto WRITE = [&](int buf) {
    char* A = lds + buf * 16384;
#pragma unroll
    for (int i = 0; i < 4; ++i) *(uint4*)(A + AwAddr[i]) = aR[i];
    char* Bb = lds + 32768 + buf * 16384;
    {
      uint4 q; q.x = pack_lo(bR[0].x, bR[1].x); q.y = pack_lo(bR[2].x, bR[3].x);
      q.z = pack_lo(bR[4].x, bR[5].x); q.w = pack_lo(bR[6].x, bR[7].x);
      *(uint4*)(Bb + BwAddr[0]) = q;
    }
    {
      uint4 q; q.x = pack_hi(bR[0].x, bR[1].x); q.y = pack_hi(bR[2].x, bR[3].x);
      q.z = pack_hi(bR[4].x, bR[5].x); q.w = pack_hi(bR[6].x, bR[7].x);
      *(uint4*)(Bb + BwAddr[1]) = q;
    }
    {
      uint4 q; q.x = pack_lo(bR[0].y, bR[1].y); q.y = pack_lo(bR[2].y, bR[3].y);
      q.z = pack_lo(bR[4].y, bR[5].y); q.w = pack_lo(bR[6].y, bR[7].y);
      *(uint4*)(Bb + BwAddr[2]) = q;
    }
    {
      uint4 q; q.x = pack_hi(bR[0].y, bR[1].y); q.y = pack_hi(bR[2].y, bR[3].y);
      q.z = pack_hi(bR[4].y, bR[5].y); q.w = pack_hi(bR[6].y, bR[7].y);
      *(uint4*)(Bb + BwAddr[3]) = q;
    }
  };

  LOAD(0);
  WRITE(0);
  __syncthreads();

  for (int t = 0; t < 32; ++t) {
    int cur = t & 1;
    if (t < 31) LOAD(t + 1);

    const char* A = lds + cur * 16384;
    const char* Bb = lds + 32768 + cur * 16384;
#pragma unroll
    for (int kk = 0; kk < 2; ++kk) {
      int kbyte = kk * 64 + ((lane >> 4) << 4);
      short8 fa[2], fg[2], fb[4];
#pragma unroll
      for (int mi = 0; mi < 2; ++mi) {
        int ra = (wv >> 1) * 32 + mi * 16 + (lane & 15);
        fa[mi] = *(const short8*)(A + ra * 128 + (kbyte ^ ((ra & 7) << 4)));
        int rg = 64 + ra;
        fg[mi] = *(const short8*)(A + rg * 128 + (kbyte ^ ((rg & 7) << 4)));
      }
#pragma unroll
      for (int ni = 0; ni < 4; ++ni) {
        int n = (wv & 1) * 64 + ni * 16 + (lane & 15);
        fb[ni] = *(const short8*)(Bb + n * 128 + (kbyte ^ (swzB(n) << 4)));
      }
#pragma unroll
      for (int mi = 0; mi < 2; ++mi)
#pragma unroll
        for (int ni = 0; ni < 4; ++ni) {
          acc_a[mi][ni] = __builtin_amdgcn_mfma_f32_16x16x32_bf16(fa[mi], fb[ni], acc_a[mi][ni], 0, 0, 0);
          acc_g[mi][ni] = __builtin_amdgcn_mfma_f32_16x16x32_bf16(fg[mi], fb[ni], acc_g[mi][ni], 0, 0, 0);
        }
    }

    if (t < 31) WRITE(cur ^ 1);
    __syncthreads();
  }

  int colb = n0 + (wv & 1) * 64;
#pragma unroll
  for (int mi = 0; mi < 2; ++mi) {
    int ob = m0 + (wv >> 1) * 32 + mi * 16 + ((lane >> 4) << 2);
#pragma unroll
    for (int q = 0; q < 4; ++q) {
      int o = ob + q;
      float ba = bout[o];
      float bg = bout[o + 2048];
#pragma unroll
      for (int ni = 0; ni < 4; ++ni) {
        float av = acc_a[mi][ni][q] + ba;
        float gv = acc_g[mi][ni][q] + bg;
        float res = av / (1.f + expf(-gv));
        int n = colb + ni * 16 + (lane & 15);
        out[(size_t)(n >> 12) * 8388608 + (size_t)o * 4096 + (n & 4095)] = res;
      }
    }
  }
}

extern "C" void kernel_launch(void* const* d_in, const int* in_sizes, int n_in,
                              void* d_out, int out_size, void* d_ws, size_t ws_size,
                              hipStream_t stream) {
  const float* u    = (const float*)d_in[0];
  const float* kern = (const float*)d_in[1];
  const float* D    = (const float*)d_in[2];
  const float* W    = (const float*)d_in[3];
  const float* bo   = (const float*)d_in[4];
  float* out = (float*)d_out;

  uint16_t* Wb = (uint16_t*)d_ws;                                      // 16 MB @ 0
  uint16_t* X  = (uint16_t*)((char*)d_ws + (size_t)16 * 1024 * 1024);  // 32 MB @ 16M
  uint16_t* XT = (uint16_t*)((char*)d_ws + (size_t)48 * 1024 * 1024);  // 32 MB @ 48M

  hipLaunchKernelGGL(cast_w_kernel,    dim3(4096), dim3(256), 0, stream, W, Wb);
  hipLaunchKernelGGL(conv_gelu_kernel, dim3(4096), dim3(256), 0, stream, u, kern, D, X);
  if (ws_size >= (size_t)80 * 1024 * 1024) {
    hipLaunchKernelGGL(transpose_kernel, dim3(4096), dim3(256), 0, stream, X, XT);
    hipLaunchKernelGGL(gemm_glu_v3,      dim3(512),  dim3(512), 0, stream, Wb, XT, bo, out);
  } else {
    hipLaunchKernelGGL(gemm_glu_v1,      dim3(2048), dim3(256), 0, stream, Wb, X, bo, out);
  }
}